// Round 22
// baseline (196.566 us; speedup 1.0000x reference)
//
#include <hip/hip_runtime.h>
#include <hip/hip_bf16.h>

typedef unsigned short u16;
typedef unsigned int   u32;
typedef unsigned long long u64;
typedef __attribute__((ext_vector_type(8))) short bf16x8;
typedef __attribute__((ext_vector_type(4))) float f32x4;
typedef __attribute__((ext_vector_type(16))) float f32x16;

#define MFMA16(a,b,c) __builtin_amdgcn_mfma_f32_16x16x32_bf16((a),(b),(c),0,0,0)
#define MFMA32(a,b,c) __builtin_amdgcn_mfma_f32_32x32x16_bf16((a),(b),(c),0,0,0)

#define GLD16(gp, lp) __builtin_amdgcn_global_load_lds( \
    (const __attribute__((address_space(1))) void*)(gp), \
    (__attribute__((address_space(3))) void*)(lp), 16, 0, 0)

__device__ inline u32 pkbf(float a, float b) {
  __hip_bfloat16 ha = __float2bfloat16(a), hb = __float2bfloat16(b);
  return (u32)(*(u16*)&ha) | ((u32)(*(u16*)&hb) << 16);
}
__device__ inline float b2f(u16 x) {
  __hip_bfloat16 h; *(u16*)&h = x; return __bfloat162float(h);
}
// fast bf16 pair pack: round (+0x8000) then byte-perm the two high halves
__device__ inline u32 pk2(float a, float b) {
  u32 ua = __builtin_bit_cast(u32, a) + 0x8000u;
  u32 ub = __builtin_bit_cast(u32, b) + 0x8000u;
  return __builtin_amdgcn_perm(ub, ua, 0x07060302u);
}
__device__ inline float fmax3(float a, float b, float c) {
  return fmaxf(fmaxf(a, b), c);
}

// ---------------------------------------------------------------- fused casts
__global__ __launch_bounds__(256) void cast_all(const float* __restrict__ x,
                                                const float* __restrict__ wq,
                                                const float* __restrict__ wk,
                                                const float* __restrict__ wv,
                                                const float* __restrict__ wo,
                                                u16* __restrict__ xb,
                                                u16* __restrict__ wqkv,
                                                u16* __restrict__ wob) {
  int i = blockIdx.x * 256 + threadIdx.x;
  const float* src; u16* dst; int off;
  if (i < 2097152)      { src = x;  dst = xb;                 off = 0; }
  else if (i < 3145728) { src = wq; dst = wqkv;               off = 2097152; }
  else if (i < 3407872) { src = wk; dst = wqkv + 4194304;     off = 3145728; }
  else if (i < 3670016) { src = wv; dst = wqkv + 5242880;     off = 3407872; }
  else                  { src = wo; dst = wob;                off = 3670016; }
  const int k = i - off;
  float4 v = reinterpret_cast<const float4*>(src)[k];
  uint2 pk; pk.x = pkbf(v.x, v.y); pk.y = pkbf(v.z, v.w);
  reinterpret_cast<uint2*>(dst)[k] = pk;
}

__device__ inline void cstore(u16* C, size_t i, float v) {
  __hip_bfloat16 h = __float2bfloat16(v); C[i] = *(u16*)&h;
}
__device__ inline void cstore(float* C, size_t i, float v) { C[i] = v; }

// ---------------------------------------------------------------- GEMM 128x384 BK=64
// C = A * B^T. Grid 32x8 = 256 blocks = ALL CUs (vs k64's 192/256). 512 thr
// = 8 waves (2M x 4N), per-wave 64x96 (acc[4][6] = 96 VGPR). 128 KiB LDS
// dbuf; per buffer (u16): A-ks0 [0,4K) | A-ks1 [4K,8K) | B-ks0 [8K,20K) |
// B-ks1 [20K,32K). A unit 128x32 (1 GLD/thr), B unit 384x32 (3 GLD/thr);
// slot-linear dest, source pre-swizzled q_log = q_phys ^ ((row>>1)&3)
// (row stride 64B; proven 2-way-free). Per K-tile: 2 phases of 24 MFMA
// with per-phase unit staging {A0,B0} then {A1,B1}; counted vmcnt(4)
// checkpoints (queue always 8: confirm oldest 4); last tile drains 0.
template<typename OutT>
__global__ __launch_bounds__(512) void gemm_w384(const u16* __restrict__ A,
                                                 const u16* __restrict__ B,
                                                 OutT* __restrict__ C,
                                                 int M, int N, int K) {
  __shared__ u16 SM[65536];   // 128 KiB: buf 32768 u16 x2

  const int t = threadIdx.x;
  const int lane = t & 63, wid = t >> 6;
  const int l15 = lane & 15, l4 = lane >> 4;
  const int wr = wid >> 2, wc = wid & 3;

  const int nwg = gridDim.x * gridDim.y;     // % 8 == 0
  int lid = blockIdx.y * gridDim.x + blockIdx.x;
  lid = (lid & 7) * (nwg >> 3) + (lid >> 3);
  const int m0 = (lid / gridDim.x) * 128, n0 = (lid % gridDim.x) * 384;

  // staging geometry
  const int ra = t >> 2, qp = t & 3;
  const int lqa = qp ^ ((ra >> 1) & 3);
  const u16* Ap = A + (size_t)(m0 + ra) * K + lqa * 8;
  const int rb0 = t >> 2,          lqb0 = qp ^ ((rb0 >> 1) & 3);
  const int rb1 = (t + 512) >> 2,  lqb1 = qp ^ ((rb1 >> 1) & 3);
  const int rb2 = (t + 1024) >> 2, lqb2 = qp ^ ((rb2 >> 1) & 3);
  const u16* Bp0 = B + (size_t)(n0 + rb0) * K + lqb0 * 8;
  const u16* Bp1 = B + (size_t)(n0 + rb1) * K + lqb1 * 8;
  const u16* Bp2 = B + (size_t)(n0 + rb2) * K + lqb2 * 8;

#define STG_A(x_, ks_) do {                                                   \
    const int bb_ = (((x_) & 1) << 15) + ((ks_) << 12);                       \
    GLD16(Ap + (x_) * 64 + (ks_) * 32, &SM[bb_ + t * 8]); } while (0)
#define STG_B(x_, ks_) do {                                                   \
    const int bb_ = (((x_) & 1) << 15) + 8192 + ((ks_) * 12288);              \
    GLD16(Bp0 + (x_) * 64 + (ks_) * 32, &SM[bb_ + t * 8]);                    \
    GLD16(Bp1 + (x_) * 64 + (ks_) * 32, &SM[bb_ + 4096 + t * 8]);             \
    GLD16(Bp2 + (x_) * 64 + (ks_) * 32, &SM[bb_ + 8192 + t * 8]); } while (0)

  // fragment reads: q = l4 ^ ((l15>>1)&3) (2-way free; row stride 64B)
  const int q = l4 ^ ((l15 >> 1) & 3);
  const int arow = wr * 64 + l15;      // + mi*16
  const int brow = wc * 96 + l15;      // + ni*16

  f32x4 acc[4][6] = {};
  const int nk = K >> 6;

  // prologue: tile 0 units in consumption order A0,B0,A1,B1 (8 GLD/thread)
  STG_A(0, 0); STG_B(0, 0); STG_A(0, 1); STG_B(0, 1);

  for (int x = 0; x < nk; ++x) {
    const int bufb = (x & 1) << 15;
    const bool pre = (x + 1 < nk);

    // ---- checkpoint 0: A0x, B0x landed (A1x, B1x stay in flight)
    asm volatile("s_waitcnt vmcnt(4)" ::: "memory");
    __builtin_amdgcn_s_barrier();
    __builtin_amdgcn_sched_barrier(0);

    bf16x8 af[4], bfr[6];
    // ---- P0: ks0 (4 + 6 ds_read, 24 MFMA)
#pragma unroll
    for (int i = 0; i < 4; ++i)
      af[i] = *(const bf16x8*)&SM[bufb + (arow + i * 16) * 32 + q * 8];
#pragma unroll
    for (int i = 0; i < 6; ++i)
      bfr[i] = *(const bf16x8*)&SM[bufb + 8192 + (brow + i * 16) * 32 + q * 8];
    if (pre) { STG_A(x + 1, 0); STG_B(x + 1, 0); }
    asm volatile("s_waitcnt lgkmcnt(0)" ::: "memory");
    __builtin_amdgcn_sched_barrier(0);
    __builtin_amdgcn_s_setprio(1);
#pragma unroll
    for (int mi = 0; mi < 4; ++mi)
#pragma unroll
      for (int ni = 0; ni < 6; ++ni)
        acc[mi][ni] = MFMA16(af[mi], bfr[ni], acc[mi][ni]);
    __builtin_amdgcn_s_setprio(0);

    // ---- checkpoint 1: A1x, B1x landed (next tile's A0,B0 stay in flight)
    if (pre) asm volatile("s_waitcnt vmcnt(4)" ::: "memory");
    else     asm volatile("s_waitcnt vmcnt(0)" ::: "memory");
    __builtin_amdgcn_s_barrier();
    __builtin_amdgcn_sched_barrier(0);

    // ---- P1: ks1 (4 + 6 ds_read, 24 MFMA)
#pragma unroll
    for (int i = 0; i < 4; ++i)
      af[i] = *(const bf16x8*)&SM[bufb + 4096 + (arow + i * 16) * 32 + q * 8];
#pragma unroll
    for (int i = 0; i < 6; ++i)
      bfr[i] = *(const bf16x8*)&SM[bufb + 20480 + (brow + i * 16) * 32 + q * 8];
    if (pre) { STG_A(x + 1, 1); STG_B(x + 1, 1); }
    asm volatile("s_waitcnt lgkmcnt(0)" ::: "memory");
    __builtin_amdgcn_sched_barrier(0);
    __builtin_amdgcn_s_setprio(1);
#pragma unroll
    for (int mi = 0; mi < 4; ++mi)
#pragma unroll
      for (int ni = 0; ni < 6; ++ni)
        acc[mi][ni] = MFMA16(af[mi], bfr[ni], acc[mi][ni]);
    __builtin_amdgcn_s_setprio(0);
  }

  const int crow = m0 + wr * 64 + (l4 << 2);
  const int ccol = n0 + wc * 96 + l15;
#pragma unroll
  for (int mi = 0; mi < 4; ++mi)
#pragma unroll
    for (int ni = 0; ni < 6; ++ni)
#pragma unroll
      for (int r = 0; r < 4; ++r)
        cstore(C, (size_t)(crow + mi * 16 + r) * N + (ccol + ni * 16), acc[mi][ni][r]);
#undef STG_A
#undef STG_B
}

// ---------------------------------------------------------------- GEMM 128x128
// Output projection. 256 thr = 4 waves (2M x 2N), triple-buffered LDS,
// counted vmcnt; 0-conflict chunk swizzle (r16-r20 proven).
template<typename OutT>
__global__ __launch_bounds__(256, 4) void gemm_sm(const u16* __restrict__ A,
                                                  const u16* __restrict__ B,
                                                  OutT* __restrict__ C,
                                                  int M, int N, int K) {
  __shared__ u16 As[3][128 * 32];   // 24K
  __shared__ u16 Bs[3][128 * 32];   // 24K

  const int t = threadIdx.x;
  const int lane = t & 63, wid = t >> 6;
  const int l15 = lane & 15, l4 = lane >> 4;
  const int wr = wid >> 1, wc = wid & 1;

  const int nwg = gridDim.x * gridDim.y;
  int lid = blockIdx.y * gridDim.x + blockIdx.x;
  lid = (lid & 7) * (nwg >> 3) + (lid >> 3);
  const int m0 = (lid / gridDim.x) * 128, n0 = (lid % gridDim.x) * 128;

  const int ra0 = t >> 2,         ca0 = (t & 3) ^ ((ra0 >> 1) & 3);
  const int ra1 = (t + 256) >> 2, ca1 = (t & 3) ^ ((ra1 >> 1) & 3);
  const u16* Ag0 = A + (size_t)(m0 + ra0) * K + ca0 * 8;
  const u16* Ag1 = A + (size_t)(m0 + ra1) * K + ca1 * 8;
  const u16* Bg0 = B + (size_t)(n0 + ra0) * K + ca0 * 8;
  const u16* Bg1 = B + (size_t)(n0 + ra1) * K + ca1 * 8;

#define STAGE(k0_, buf_) do {                                                 \
    GLD16(Ag0 + (k0_), &As[buf_][t * 8]);                                     \
    GLD16(Ag1 + (k0_), &As[buf_][2048 + t * 8]);                              \
    GLD16(Bg0 + (k0_), &Bs[buf_][t * 8]);                                     \
    GLD16(Bg1 + (k0_), &Bs[buf_][2048 + t * 8]);                              \
  } while (0)

  const int nk = K >> 5;
  const int ks = (l15 >> 1) & 3;
  const int coff = ((l4 ^ ks) << 3);

  f32x4 acc[4][4] = {};

  STAGE(0, 0);
  if (nk > 1) STAGE(32, 1);
  if (nk > 2) STAGE(64, 2);

  int cur = 0;
  for (int j = 0; j < nk; ++j) {
    if (j + 2 < nk)      asm volatile("s_waitcnt vmcnt(8)" ::: "memory");
    else if (j + 1 < nk) asm volatile("s_waitcnt vmcnt(4)" ::: "memory");
    else                 asm volatile("s_waitcnt vmcnt(0)" ::: "memory");
    __builtin_amdgcn_s_barrier();
    __builtin_amdgcn_sched_barrier(0);

    bf16x8 af[4], bfr[4];
#pragma unroll
    for (int mi = 0; mi < 4; ++mi)
      af[mi] = *(const bf16x8*)&As[cur][(wr * 64 + mi * 16 + l15) * 32 + coff];
#pragma unroll
    for (int ni = 0; ni < 4; ++ni)
      bfr[ni] = *(const bf16x8*)&Bs[cur][(wc * 64 + ni * 16 + l15) * 32 + coff];
    __builtin_amdgcn_s_setprio(1);
#pragma unroll
    for (int mi = 0; mi < 4; ++mi)
#pragma unroll
      for (int ni = 0; ni < 4; ++ni)
        acc[mi][ni] = MFMA16(af[mi], bfr[ni], acc[mi][ni]);
    __builtin_amdgcn_s_setprio(0);

    __builtin_amdgcn_s_barrier();
    if (j + 3 < nk) STAGE((j + 3) << 5, cur);
    cur = (cur == 2) ? 0 : cur + 1;
  }

  const int crow = m0 + wr * 64 + (l4 << 2);
  const int ccol = n0 + wc * 64 + l15;
#pragma unroll
  for (int mi = 0; mi < 4; ++mi)
#pragma unroll
    for (int ni = 0; ni < 4; ++ni)
#pragma unroll
      for (int r = 0; r < 4; ++r)
        cstore(C, (size_t)(crow + mi * 16 + r) * N + (ccol + ni * 16), acc[mi][ni][r]);
#undef STAGE
}

// ---------------------------------------------------------------- RMSNorm+RoPE | Vtrans
// Merged launch: blocks [0,20480) do rmsrope (qkv cols < 2560); blocks
// [20480, 20736) do the V transpose (reads cols >= 2560) -> independent.
__global__ __launch_bounds__(256) void rope_vtrans(u16* __restrict__ qkv,
                                                   u16* __restrict__ vt) {
  __shared__ u16 Ls[64 * 130];
  const int bid = blockIdx.x;
  const int t = threadIdx.x;
  if (bid < 20480) {
    const int lane = t & 63;
    const int gw = bid * 4 + (t >> 6);
    const int row = gw / 20;
    const int hd = gw - row * 20;
    const int col = (hd < 16) ? hd * 128 : 2048 + (hd - 16) * 128;
    const size_t base = (size_t)row * 3072 + col;
    float x1 = b2f(qkv[base + lane]);
    float x2 = b2f(qkv[base + 64 + lane]);
    float ss = x1 * x1 + x2 * x2;
#pragma unroll
    for (int off = 32; off >= 1; off >>= 1) ss += __shfl_xor(ss, off, 64);
    const float qsc = (hd < 16) ? (0.08838834764831845f * 1.44269504088896340f)
                                : 1.0f;
    const float sc = rsqrtf(ss * (1.0f / 128.0f) + 1e-6f) * qsc;
    const int pos = row & 2047;
    const float inv_freq = exp2f(-(float)lane * (13.287712379549449f / 64.0f));
    float sn, cs;
    sincosf((float)pos * inv_freq, &sn, &cs);
    const float a = x1 * sc, b2 = x2 * sc;
    __hip_bfloat16 o1 = __float2bfloat16(a * cs - b2 * sn);
    __hip_bfloat16 o2 = __float2bfloat16(a * sn + b2 * cs);
    qkv[base + lane] = *(u16*)&o1;
    qkv[base + 64 + lane] = *(u16*)&o2;
  } else {
    const int vb = bid - 20480;
    const int g = vb & 7, sb = vb >> 3;
    const int b = g >> 2, kvh = g & 3;
    const int vcol = 2560 + kvh * 128;
    {
      const int row = t >> 4, dch = t & 15;
      const u16* src = qkv + (size_t)(b * 2048 + sb * 64 + row) * 3072 + vcol + dch * 8;
#pragma unroll
      for (int it = 0; it < 4; ++it) {
        bf16x8 v = *(const bf16x8*)(src + (size_t)it * 16 * 3072);
        *(bf16x8*)&Ls[(row + it * 16) * 130 + dch * 8] = v;
      }
    }
    __syncthreads();
    const int c = t & 7, d0 = t >> 3;
    const int k0 = 4 * (8 * (c >> 2) + 4 * ((c >> 1) & 1) + (c & 1));
#pragma unroll
    for (int it = 0; it < 4; ++it) {
      const int d = d0 + 32 * it;
      u16 v[8];
#pragma unroll
      for (int e = 0; e < 8; ++e)
        v[e] = Ls[(k0 + (e & 3) + 8 * (e >> 2)) * 130 + d];
      u64 lo = (u64)v[0] | ((u64)v[1] << 16) | ((u64)v[2] << 32) | ((u64)v[3] << 48);
      u64 hi = (u64)v[4] | ((u64)v[5] << 16) | ((u64)v[6] << 32) | ((u64)v[7] << 48);
      u64* dst = (u64*)(vt + ((size_t)g * 128 + d) * 2048 + sb * 64 + c * 8);
      dst[0] = lo; dst[1] = hi;
    }
  }
}

// ---------------------------------------------------------------- flash attention
// r19 version (best): deferred cross-half max; 512 blocks x 256 thr = 4
// waves (2 qg x 2 k-halves); q64-tile pair (j, 31-j) sequential (33 iters);
// counted vmcnt(8) pipeline, 2 barriers/iter; zero-shuffle PV via
// sigma-ordered vt; XOR bank swizzles; defer-max; exp2-domain Q prescale.
__global__ __launch_bounds__(256, 2) void attn_kernel(const u16* __restrict__ qkv,
                                                      const u16* __restrict__ vt,
                                                      u16* __restrict__ ao) {
  __shared__ u16 Ks[2][64 * 128];   // [k][d], 16B chunks XORed by k&7 (32K)
  __shared__ u16 Vt[2][128 * 64];   // [d][sigma(k)], chunks XORed by d&7 (32K)

  const int t = threadIdx.x;
  const int lane = t & 63, w = t >> 6;
  const int l31 = lane & 31, hi = lane >> 5;
  const int qg = w >> 1, hi2 = w & 1;

  const int bid = blockIdx.x;
  const int g = bid & 7;                  // XCD group = (b, kvh)
  const int b = g >> 2, kvh = g & 3;
  const int idx = bid >> 3;
  const int h = kvh * 4 + (idx & 3);
  const int j = idx >> 2;                 // 0..15 -> pair (j, 31-j)

  const int kcol = 2048 + kvh * 128;
  const u16* vtg = vt + (size_t)g * 128 * 2048;

  const int krow_s = t >> 4, kchk = t & 15;   // K staging (4 GLD/thread)
  const int vd = t >> 3, vc = t & 7;          // V staging (4 GLD/thread)

#define STAGE_K(kb_, buf_) do {                                               \
    const size_t rb_ = (size_t)(b * 2048 + (kb_) * 64);                       \
    _Pragma("unroll")                                                         \
    for (int j_ = 0; j_ < 4; ++j_) {                                          \
      const int row_ = j_ * 16 + krow_s;                                      \
      GLD16(qkv + (rb_ + row_) * 3072 + kcol + ((kchk ^ (row_ & 7)) << 3),    \
            &Ks[buf_][(j_ * 256 + t) << 3]);                                  \
    } } while (0)

#define STAGE_V(kb_, buf_) do {                                               \
    _Pragma("unroll")                                                         \
    for (int j_ = 0; j_ < 4; ++j_) {                                          \
      const int d_ = j_ * 32 + vd;                                            \
      GLD16(vtg + (size_t)d_ * 2048 + (kb_) * 64 + ((vc ^ (d_ & 7)) << 3),    \
            &Vt[buf_][(j_ * 256 + t) << 3]);                                  \
    } } while (0)

  for (int ph = 0; ph < 2; ++ph) {
    const int qt64 = ph ? (31 - j) : j;
    const int q0 = qt64 * 64;
    const int nt = qt64 + 1;
    const int qrow = q0 + 32 * qg + l31;

    // Q fragments (B operand): col=q, k = st*16 + hi*8 + e (pre-scaled)
    bf16x8 qf[8];
    {
      const u16* qp = qkv + (size_t)(b * 2048 + qrow) * 3072 + h * 128 + hi * 8;
#pragma unroll
      for (int st = 0; st < 8; ++st) qf[st] = *(const bf16x8*)(qp + st * 16);
    }

    f32x16 o[4];
#pragma unroll
    for (int dt = 0; dt < 4; ++dt)
#pragma unroll
      for (int i = 0; i < 16; ++i) o[dt][i] = 0.f;
    float m2 = -1e30f, l = 0.f;

    // prologue: stage batches 0 and 1
    STAGE_K(0, 0);
    STAGE_V(0, 0);
    if (nt > 1) { STAGE_K(1, 1); STAGE_V(1, 1); }

    for (int kb = 0; kb < nt; ++kb) {
      const int cur = kb & 1;
      if (kb + 1 < nt) asm volatile("s_waitcnt vmcnt(8)" ::: "memory");
      else             asm volatile("s_waitcnt vmcnt(0)" ::: "memory");
      __builtin_amdgcn_s_barrier();
      __builtin_amdgcn_sched_barrier(0);

      // ---- S^T = K_half Q^T  (rows k of this wave's 32-half, cols q)
      f32x16 s;
#pragma unroll
      for (int i = 0; i < 16; ++i) s[i] = 0.f;
      const int kbase = (32 * hi2 + l31) * 128;
      const int ksw = l31 & 7;
      __builtin_amdgcn_s_setprio(1);
#pragma unroll
      for (int st = 0; st < 8; ++st) {
        bf16x8 ka = *(const bf16x8*)&Ks[cur][kbase + (((2 * st + hi) ^ ksw) << 3)];
        s = MFMA32(ka, qf[st], s);
      }
      __builtin_amdgcn_s_setprio(0);

      // ---- mask (diag only), max3-tree LOCAL row max (no cross-half shfl)
      const bool nomask = (kb < qt64) || (hi2 == 0 && qg == 1);
      if (!nomask) {
#pragma unroll
        for (int i = 0; i < 16; ++i) {
          const int kr = kb * 64 + 32 * hi2 + (i & 3) + 8 * (i >> 2) + 4 * hi;
          s[i] = (kr <= qrow) ? s[i] : -INFINITY;
        }
      }
      float a0 = fmax3(s[0], s[1], s[2]);
      float a1 = fmax3(s[3], s[4], s[5]);
      float a2 = fmax3(s[6], s[7], s[8]);
      float a3 = fmax3(s[9], s[10], s[11]);
      float a4 = fmax3(s[12], s[13], s[14]);
      float b0 = fmax3(a0, a1, s[15]);
      float b1 = fmax3(a2, a3, a4);
      float pm = fmaxf(b0, b1);
      // ---- defer-max rescale; __all spans all 64 lanes -> local test is
      // equivalent to full-row max test; shuffle only inside the rare branch.
      if (!__all(pm <= m2 + 8.f)) {
        const float pmf = fmaxf(pm, __shfl_xor(pm, 32));
        const float m2n = fmaxf(m2, pmf);
        const float fc = exp2f(m2 - m2n);
        m2 = m2n; l *= fc;
#pragma unroll
        for (int dt = 0; dt < 4; ++dt)
#pragma unroll
          for (int i = 0; i < 16; ++i) o[dt][i] *= fc;
      }
      // ---- P = exp2(z - m2), tree local sum (cross-hi deferred)
#pragma unroll
      for (int i = 0; i < 16; ++i) s[i] = exp2f(s[i] - m2);
      float t8[8];
#pragma unroll
      for (int i = 0; i < 8; ++i) t8[i] = s[i] + s[i + 8];
#pragma unroll
      for (int i = 0; i < 4; ++i) t8[i] = t8[i] + t8[i + 4];
      l += (t8[0] + t8[1]) + (t8[2] + t8[3]);
      // ---- P C-regs -> B-operand directly (sigma order, perm pack)
      union PB { u32 wd[4]; bf16x8 v; } p0u, p1u;
#pragma unroll
      for (int q_ = 0; q_ < 4; ++q_) {
        p0u.wd[q_] = pk2(s[2 * q_],     s[2 * q_ + 1]);
        p1u.wd[q_] = pk2(s[8 + 2 * q_], s[8 + 2 * q_ + 1]);
      }
      // ---- O^T += V^T_half P_half  (rows d, cols q)
      __builtin_amdgcn_s_setprio(1);
#pragma unroll
      for (int dt = 0; dt < 4; ++dt) {
        const int vrow = (dt * 32 + l31) * 64;
        const int dsw = l31 & 7;
        bf16x8 va0 = *(const bf16x8*)&Vt[cur][vrow + (((4 * hi2 + hi) ^ dsw) << 3)];
        o[dt] = MFMA32(va0, p0u.v, o[dt]);
        bf16x8 va1 = *(const bf16x8*)&Vt[cur][vrow + (((4 * hi2 + 2 + hi) ^ dsw) << 3)];
        o[dt] = MFMA32(va1, p1u.v, o[dt]);
      }
      __builtin_amdgcn_s_setprio(0);

      __builtin_amdgcn_s_barrier();          // all waves done reading buf[cur]
      if (kb + 2 < nt) { STAGE_K(kb + 2, cur); STAGE_V(kb + 2, cur); }
    }

    // ---- in-block merge of the two k-halves (per q-group)
    __syncthreads();                 // all compute done; Ks/Vt reusable
    const float l_tot = l + __shfl_xor(l, 32);
    float* Mrg = (float*)&Ks[0][0];
    float* Mlb = (float*)&Vt[0][0];
    const int sw8 = l31 & 7;
    if (hi2) {
#pragma unroll
      for (int dt = 0; dt < 4; ++dt) {
        const int rbase = ((qg * 4 + dt) * 32 + l31) * 32;
#pragma unroll
        for (int m_ = 0; m_ < 4; ++m_) {
          f32x4 cv;
          cv[0] = o[dt][4 * m_ + 0]; cv[1] = o[dt][4 * m_ + 1];
          cv[2] = o[dt][4 * m_ + 2]; cv[3] = o[dt][4 * m_ + 3];
          *(f32x4*)&Mrg[rbase + (((hi * 4 + m_) ^ sw8) << 2)] = cv;
        }
      }
      if (hi == 0) {
        Mlb[qg * 64 + l31] = m2;
        Mlb[qg * 64 + 32 + l31] = l_tot;
      }
    }
    __syncthreads();
    if (!hi2) {
      const float m1 = Mlb[qg * 64 + l31];
      const float l1 = Mlb[qg * 64 + 32 + l31];
      const float ms = fmaxf(m2, m1);
      const float w0 = exp2f(m2 - ms), w1 = exp2f(m1 - ms);
      const float inv = 1.f / (w0 * l_tot + w1 * l1);
      const float aw0 = w0 * inv, aw1 = w1 * inv;
      const size_t orow = (size_t)(b * 2048 + qrow) * 2048 + h * 128;
#pragma unroll
      for (int dt = 0; dt < 4; ++dt) {
        const int rbase = ((qg * 4 + dt) * 32 + l31) * 32;
#pragma unroll
        for (int m_ = 0; m_ < 4; ++m_) {
          f32x4 o1v = *(const f32x4*)&Mrg[rbase + (((hi * 4 + m_) ^ sw8) << 2)];
          u64 val = 0;
#pragma unroll
          for (int r = 0; r < 4; ++r) {
            __hip_bfloat16 hb =
                __float2bfloat16(aw0 * o[dt][4 * m_ + r] + aw1 * o1v[r]);
            val |= (u64)(*(u16*)&hb) << (16 * r);
          }
          *(u64*)&ao[orow + dt * 32 + 8 * m_ + 4 * hi] = val;
        }
      }
    }
    __syncthreads();                 // protect Mrg/Mlb before next-phase staging
  }
#undef STAGE_K
#undef STAGE_V
}

// ---------------------------------------------------------------- launch
extern "C" void kernel_launch(void* const* d_in, const int* in_sizes, int n_in,
                              void* d_out, int out_size, void* d_ws, size_t ws_size,
                              hipStream_t stream) {
  const float* x  = (const float*)d_in[0];
  const float* wq = (const float*)d_in[2];
  const float* wk = (const float*)d_in[3];
  const float* wv = (const float*)d_in[4];
  const float* wo = (const float*)d_in[5];
  float* out = (float*)d_out;

  u16* xb   = (u16*)d_ws;                       // x bf16   [4096][2048]
  u16* wqkv = xb + (size_t)8388608;             // W bf16   [3072][2048]
  u16* qkv  = wqkv + (size_t)6291456;           // qkv      [4096][3072]
  u16* vtg  = qkv + (size_t)12582912;           // V^T      [8][128][2048]
  u16* wob  = vtg + (size_t)2097152;            // wo bf16  [2048][2048]
  u16* ao   = xb;                               // attn out [4096][2048] (reuse xb)

  cast_all<<<18432, 256, 0, stream>>>(x, wq, wk, wv, wo, xb, wqkv, wob);

  gemm_w384<u16><<<dim3(8, 32), 512, 0, stream>>>(xb, wqkv, qkv, 4096, 3072, 2048);

  rope_vtrans<<<20736, 256, 0, stream>>>(qkv, vtg);

  attn_kernel<<<512, 256, 0, stream>>>(qkv, vtg, ao);

  gemm_sm<float><<<dim3(16, 32), 256, 0, stream>>>(ao, wob, out, 4096, 2048, 2048);
}

// Round 23
// 193.327 us; speedup vs baseline: 1.0168x; 1.0168x over previous
//
#include <hip/hip_runtime.h>
#include <hip/hip_bf16.h>

typedef unsigned short u16;
typedef unsigned int   u32;
typedef unsigned long long u64;
typedef __attribute__((ext_vector_type(8))) short bf16x8;
typedef __attribute__((ext_vector_type(4))) float f32x4;
typedef __attribute__((ext_vector_type(16))) float f32x16;

#define MFMA16(a,b,c) __builtin_amdgcn_mfma_f32_16x16x32_bf16((a),(b),(c),0,0,0)
#define MFMA32(a,b,c) __builtin_amdgcn_mfma_f32_32x32x16_bf16((a),(b),(c),0,0,0)

#define GLD16(gp, lp) __builtin_amdgcn_global_load_lds( \
    (const __attribute__((address_space(1))) void*)(gp), \
    (__attribute__((address_space(3))) void*)(lp), 16, 0, 0)

__device__ inline u32 pkbf(float a, float b) {
  __hip_bfloat16 ha = __float2bfloat16(a), hb = __float2bfloat16(b);
  return (u32)(*(u16*)&ha) | ((u32)(*(u16*)&hb) << 16);
}
__device__ inline float b2f(u16 x) {
  __hip_bfloat16 h; *(u16*)&h = x; return __bfloat162float(h);
}
// fast bf16 pair pack: round (+0x8000) then byte-perm the two high halves
__device__ inline u32 pk2(float a, float b) {
  u32 ua = __builtin_bit_cast(u32, a) + 0x8000u;
  u32 ub = __builtin_bit_cast(u32, b) + 0x8000u;
  return __builtin_amdgcn_perm(ub, ua, 0x07060302u);
}
__device__ inline float fmax3(float a, float b, float c) {
  return fmaxf(fmaxf(a, b), c);
}

// ---------------------------------------------------------------- fused casts
__global__ __launch_bounds__(256) void cast_all(const float* __restrict__ x,
                                                const float* __restrict__ wq,
                                                const float* __restrict__ wk,
                                                const float* __restrict__ wv,
                                                const float* __restrict__ wo,
                                                u16* __restrict__ xb,
                                                u16* __restrict__ wqkv,
                                                u16* __restrict__ wob) {
  int i = blockIdx.x * 256 + threadIdx.x;
  const float* src; u16* dst; int off;
  if (i < 2097152)      { src = x;  dst = xb;                 off = 0; }
  else if (i < 3145728) { src = wq; dst = wqkv;               off = 2097152; }
  else if (i < 3407872) { src = wk; dst = wqkv + 4194304;     off = 3145728; }
  else if (i < 3670016) { src = wv; dst = wqkv + 5242880;     off = 3407872; }
  else                  { src = wo; dst = wob;                off = 3670016; }
  const int k = i - off;
  float4 v = reinterpret_cast<const float4*>(src)[k];
  uint2 pk; pk.x = pkbf(v.x, v.y); pk.y = pkbf(v.z, v.w);
  reinterpret_cast<uint2*>(dst)[k] = pk;
}

__device__ inline void cstore(u16* C, size_t i, float v) {
  __hip_bfloat16 h = __float2bfloat16(v); C[i] = *(u16*)&h;
}
__device__ inline void cstore(float* C, size_t i, float v) { C[i] = v; }

// ---------------------------------------------------------------- GEMM 256x256 BK=64
// C = A * B^T. 512 thr = 8 waves (2M x 4N), per-wave 128x64 (acc[8][4]).
// 128 KiB LDS dbuf; per buffer 4 regions (u16): A-ks0 [0,8K) | A-ks1 [8K,16K)
// | B-ks0 [16K,24K) | B-ks1 [24K,32K). Each region: 256 rows x 32 u16,
// slot-linear (slot=4*row+q -> slot*16B), source pre-swizzled with the
// PROVEN 2-way-free key q_log = q_phys ^ ((row>>1)&3) (row stride 64B).
// Schedule per K-tile x: 4 phases of 16 MFMA; stage one unit of tile x+1
// per phase in consumption order (A0,B0,A1,B1); TWO counted vmcnt(4)
// checkpoints (before P0 and P2) + 2 barriers per 64-MFMA tile; never a
// full drain mid-loop. (r21 measured best: ~59us @ 192 blocks.)
template<typename OutT>
__global__ __launch_bounds__(512, 2) void gemm_k64(const u16* __restrict__ A,
                                                   const u16* __restrict__ B,
                                                   OutT* __restrict__ C,
                                                   int M, int N, int K) {
  __shared__ u16 SM[65536];   // 128 KiB

  const int t = threadIdx.x;
  const int lane = t & 63, wid = t >> 6;
  const int l15 = lane & 15, l4 = lane >> 4;
  const int wr = wid >> 2, wc = wid & 3;

  const int nwg = gridDim.x * gridDim.y;     // % 8 == 0
  int lid = blockIdx.y * gridDim.x + blockIdx.x;
  lid = (lid & 7) * (nwg >> 3) + (lid >> 3);
  const int m0 = (lid / gridDim.x) * 256, n0 = (lid % gridDim.x) * 256;

  // staging: slot s in {t, t+512}; row = s>>2, q_phys = s&3,
  // logical chunk = q_phys ^ ((row>>1)&3); global kcol = x*64 + ks*32 + lq*8
  const int r0 = t >> 2, q0p = t & 3;
  const int lq0 = q0p ^ ((r0 >> 1) & 3);
  const int r1 = r0 + 128;
  const int lq1 = q0p ^ ((r1 >> 1) & 3);
  const u16* Ap0 = A + (size_t)(m0 + r0) * K + lq0 * 8;
  const u16* Ap1 = A + (size_t)(m0 + r1) * K + lq1 * 8;
  const u16* Bp0 = B + (size_t)(n0 + r0) * K + lq0 * 8;
  const u16* Bp1 = B + (size_t)(n0 + r1) * K + lq1 * 8;

#define STG_A(x_, ks_) do {                                                   \
    const int bb_ = (((x_) & 1) << 15) + ((ks_) << 13);                       \
    GLD16(Ap0 + (x_) * 64 + (ks_) * 32, &SM[bb_ + t * 8]);                    \
    GLD16(Ap1 + (x_) * 64 + (ks_) * 32, &SM[bb_ + 4096 + t * 8]); } while (0)
#define STG_B(x_, ks_) do {                                                   \
    const int bb_ = (((x_) & 1) << 15) + 16384 + ((ks_) << 13);               \
    GLD16(Bp0 + (x_) * 64 + (ks_) * 32, &SM[bb_ + t * 8]);                    \
    GLD16(Bp1 + (x_) * 64 + (ks_) * 32, &SM[bb_ + 4096 + t * 8]); } while (0)

  // fragment reads: q = l4 ^ ((l15>>1)&3) (2-way free; row stride 64B)
  const int q = l4 ^ ((l15 >> 1) & 3);
  const int arow = wr * 128 + l15;     // + mi*16 (+64 for m-frags 4-7)
  const int brow = wc * 64 + l15;      // + ni*16

  f32x4 acc[8][4] = {};
  const int nk = K >> 6;

  // prologue: tile 0 units in consumption order
  STG_A(0, 0); STG_B(0, 0); STG_A(0, 1); STG_B(0, 1);

  for (int x = 0; x < nk; ++x) {
    const int bufb = (x & 1) << 15;
    const bool pre = (x + 1 < nk);

    // ---- checkpoint: A0x, B0x landed (A1x, B1x stay in flight)
    asm volatile("s_waitcnt vmcnt(4)" ::: "memory");
    __builtin_amdgcn_s_barrier();
    __builtin_amdgcn_sched_barrier(0);

    bf16x8 af[4], bfr[4];
    // ---- P0: ks0, m-frags 0-3 (8 ds_read)
#pragma unroll
    for (int i = 0; i < 4; ++i)
      af[i] = *(const bf16x8*)&SM[bufb + (arow + i * 16) * 32 + q * 8];
#pragma unroll
    for (int i = 0; i < 4; ++i)
      bfr[i] = *(const bf16x8*)&SM[bufb + 16384 + (brow + i * 16) * 32 + q * 8];
    if (pre) STG_A(x + 1, 0);
    asm volatile("s_waitcnt lgkmcnt(0)" ::: "memory");
    __builtin_amdgcn_sched_barrier(0);
    __builtin_amdgcn_s_setprio(1);
#pragma unroll
    for (int mi = 0; mi < 4; ++mi)
#pragma unroll
      for (int ni = 0; ni < 4; ++ni)
        acc[mi][ni] = MFMA16(af[mi], bfr[ni], acc[mi][ni]);
    __builtin_amdgcn_s_setprio(0);

    // ---- P1: ks0, m-frags 4-7 (4 ds_read; bfr reused)
#pragma unroll
    for (int i = 0; i < 4; ++i)
      af[i] = *(const bf16x8*)&SM[bufb + (arow + 64 + i * 16) * 32 + q * 8];
    if (pre) STG_B(x + 1, 0);
    asm volatile("s_waitcnt lgkmcnt(0)" ::: "memory");
    __builtin_amdgcn_sched_barrier(0);
    __builtin_amdgcn_s_setprio(1);
#pragma unroll
    for (int mi = 0; mi < 4; ++mi)
#pragma unroll
      for (int ni = 0; ni < 4; ++ni)
        acc[4 + mi][ni] = MFMA16(af[mi], bfr[ni], acc[4 + mi][ni]);
    __builtin_amdgcn_s_setprio(0);

    // ---- checkpoint: A1x, B1x landed (next tile's A0,B0 stay in flight)
    if (pre) asm volatile("s_waitcnt vmcnt(4)" ::: "memory");
    else     asm volatile("s_waitcnt vmcnt(0)" ::: "memory");
    __builtin_amdgcn_s_barrier();
    __builtin_amdgcn_sched_barrier(0);

    // ---- P2: ks1, m-frags 0-3 (8 ds_read)
#pragma unroll
    for (int i = 0; i < 4; ++i)
      af[i] = *(const bf16x8*)&SM[bufb + 8192 + (arow + i * 16) * 32 + q * 8];
#pragma unroll
    for (int i = 0; i < 4; ++i)
      bfr[i] = *(const bf16x8*)&SM[bufb + 24576 + (brow + i * 16) * 32 + q * 8];
    if (pre) STG_A(x + 1, 1);
    asm volatile("s_waitcnt lgkmcnt(0)" ::: "memory");
    __builtin_amdgcn_sched_barrier(0);
    __builtin_amdgcn_s_setprio(1);
#pragma unroll
    for (int mi = 0; mi < 4; ++mi)
#pragma unroll
      for (int ni = 0; ni < 4; ++ni)
        acc[mi][ni] = MFMA16(af[mi], bfr[ni], acc[mi][ni]);
    __builtin_amdgcn_s_setprio(0);

    // ---- P3: ks1, m-frags 4-7 (4 ds_read)
#pragma unroll
    for (int i = 0; i < 4; ++i)
      af[i] = *(const bf16x8*)&SM[bufb + 8192 + (arow + 64 + i * 16) * 32 + q * 8];
    if (pre) STG_B(x + 1, 1);
    asm volatile("s_waitcnt lgkmcnt(0)" ::: "memory");
    __builtin_amdgcn_sched_barrier(0);
    __builtin_amdgcn_s_setprio(1);
#pragma unroll
    for (int mi = 0; mi < 4; ++mi)
#pragma unroll
      for (int ni = 0; ni < 4; ++ni)
        acc[4 + mi][ni] = MFMA16(af[mi], bfr[ni], acc[4 + mi][ni]);
    __builtin_amdgcn_s_setprio(0);
  }

  const int crow = m0 + wr * 128 + (l4 << 2);
  const int ccol = n0 + wc * 64 + l15;
#pragma unroll
  for (int mi = 0; mi < 8; ++mi)
#pragma unroll
    for (int ni = 0; ni < 4; ++ni)
#pragma unroll
      for (int r = 0; r < 4; ++r)
        cstore(C, (size_t)(crow + mi * 16 + r) * N + (ccol + ni * 16), acc[mi][ni][r]);
#undef STG_A
#undef STG_B
}

// ---------------------------------------------------------------- GEMM 128x128
// Output projection. 256 thr = 4 waves (2M x 2N), triple-buffered LDS,
// counted vmcnt; 0-conflict chunk swizzle (r16-r20 proven).
template<typename OutT>
__global__ __launch_bounds__(256, 4) void gemm_sm(const u16* __restrict__ A,
                                                  const u16* __restrict__ B,
                                                  OutT* __restrict__ C,
                                                  int M, int N, int K) {
  __shared__ u16 As[3][128 * 32];   // 24K
  __shared__ u16 Bs[3][128 * 32];   // 24K

  const int t = threadIdx.x;
  const int lane = t & 63, wid = t >> 6;
  const int l15 = lane & 15, l4 = lane >> 4;
  const int wr = wid >> 1, wc = wid & 1;

  const int nwg = gridDim.x * gridDim.y;
  int lid = blockIdx.y * gridDim.x + blockIdx.x;
  lid = (lid & 7) * (nwg >> 3) + (lid >> 3);
  const int m0 = (lid / gridDim.x) * 128, n0 = (lid % gridDim.x) * 128;

  const int ra0 = t >> 2,         ca0 = (t & 3) ^ ((ra0 >> 1) & 3);
  const int ra1 = (t + 256) >> 2, ca1 = (t & 3) ^ ((ra1 >> 1) & 3);
  const u16* Ag0 = A + (size_t)(m0 + ra0) * K + ca0 * 8;
  const u16* Ag1 = A + (size_t)(m0 + ra1) * K + ca1 * 8;
  const u16* Bg0 = B + (size_t)(n0 + ra0) * K + ca0 * 8;
  const u16* Bg1 = B + (size_t)(n0 + ra1) * K + ca1 * 8;

#define STAGE(k0_, buf_) do {                                                 \
    GLD16(Ag0 + (k0_), &As[buf_][t * 8]);                                     \
    GLD16(Ag1 + (k0_), &As[buf_][2048 + t * 8]);                              \
    GLD16(Bg0 + (k0_), &Bs[buf_][t * 8]);                                     \
    GLD16(Bg1 + (k0_), &Bs[buf_][2048 + t * 8]);                              \
  } while (0)

  const int nk = K >> 5;
  const int ks = (l15 >> 1) & 3;
  const int coff = ((l4 ^ ks) << 3);

  f32x4 acc[4][4] = {};

  STAGE(0, 0);
  if (nk > 1) STAGE(32, 1);
  if (nk > 2) STAGE(64, 2);

  int cur = 0;
  for (int j = 0; j < nk; ++j) {
    if (j + 2 < nk)      asm volatile("s_waitcnt vmcnt(8)" ::: "memory");
    else if (j + 1 < nk) asm volatile("s_waitcnt vmcnt(4)" ::: "memory");
    else                 asm volatile("s_waitcnt vmcnt(0)" ::: "memory");
    __builtin_amdgcn_s_barrier();
    __builtin_amdgcn_sched_barrier(0);

    bf16x8 af[4], bfr[4];
#pragma unroll
    for (int mi = 0; mi < 4; ++mi)
      af[mi] = *(const bf16x8*)&As[cur][(wr * 64 + mi * 16 + l15) * 32 + coff];
#pragma unroll
    for (int ni = 0; ni < 4; ++ni)
      bfr[ni] = *(const bf16x8*)&Bs[cur][(wc * 64 + ni * 16 + l15) * 32 + coff];
    __builtin_amdgcn_s_setprio(1);
#pragma unroll
    for (int mi = 0; mi < 4; ++mi)
#pragma unroll
      for (int ni = 0; ni < 4; ++ni)
        acc[mi][ni] = MFMA16(af[mi], bfr[ni], acc[mi][ni]);
    __builtin_amdgcn_s_setprio(0);

    __builtin_amdgcn_s_barrier();
    if (j + 3 < nk) STAGE((j + 3) << 5, cur);
    cur = (cur == 2) ? 0 : cur + 1;
  }

  const int crow = m0 + wr * 64 + (l4 << 2);
  const int ccol = n0 + wc * 64 + l15;
#pragma unroll
  for (int mi = 0; mi < 4; ++mi)
#pragma unroll
    for (int ni = 0; ni < 4; ++ni)
#pragma unroll
      for (int r = 0; r < 4; ++r)
        cstore(C, (size_t)(crow + mi * 16 + r) * N + (ccol + ni * 16), acc[mi][ni][r]);
#undef STAGE
}

// ---------------------------------------------------------------- RMSNorm+RoPE | Vtrans
// Merged launch: blocks [0,20480) do rmsrope (qkv cols < 2560); blocks
// [20480, 20736) do the V transpose (reads cols >= 2560) -> independent.
__global__ __launch_bounds__(256) void rope_vtrans(u16* __restrict__ qkv,
                                                   u16* __restrict__ vt) {
  __shared__ u16 Ls[64 * 130];
  const int bid = blockIdx.x;
  const int t = threadIdx.x;
  if (bid < 20480) {
    const int lane = t & 63;
    const int gw = bid * 4 + (t >> 6);
    const int row = gw / 20;
    const int hd = gw - row * 20;
    const int col = (hd < 16) ? hd * 128 : 2048 + (hd - 16) * 128;
    const size_t base = (size_t)row * 3072 + col;
    float x1 = b2f(qkv[base + lane]);
    float x2 = b2f(qkv[base + 64 + lane]);
    float ss = x1 * x1 + x2 * x2;
#pragma unroll
    for (int off = 32; off >= 1; off >>= 1) ss += __shfl_xor(ss, off, 64);
    const float qsc = (hd < 16) ? (0.08838834764831845f * 1.44269504088896340f)
                                : 1.0f;
    const float sc = rsqrtf(ss * (1.0f / 128.0f) + 1e-6f) * qsc;
    const int pos = row & 2047;
    const float inv_freq = exp2f(-(float)lane * (13.287712379549449f / 64.0f));
    float sn, cs;
    sincosf((float)pos * inv_freq, &sn, &cs);
    const float a = x1 * sc, b2 = x2 * sc;
    __hip_bfloat16 o1 = __float2bfloat16(a * cs - b2 * sn);
    __hip_bfloat16 o2 = __float2bfloat16(a * sn + b2 * cs);
    qkv[base + lane] = *(u16*)&o1;
    qkv[base + 64 + lane] = *(u16*)&o2;
  } else {
    const int vb = bid - 20480;
    const int g = vb & 7, sb = vb >> 3;
    const int b = g >> 2, kvh = g & 3;
    const int vcol = 2560 + kvh * 128;
    {
      const int row = t >> 4, dch = t & 15;
      const u16* src = qkv + (size_t)(b * 2048 + sb * 64 + row) * 3072 + vcol + dch * 8;
#pragma unroll
      for (int it = 0; it < 4; ++it) {
        bf16x8 v = *(const bf16x8*)(src + (size_t)it * 16 * 3072);
        *(bf16x8*)&Ls[(row + it * 16) * 130 + dch * 8] = v;
      }
    }
    __syncthreads();
    const int c = t & 7, d0 = t >> 3;
    const int k0 = 4 * (8 * (c >> 2) + 4 * ((c >> 1) & 1) + (c & 1));
#pragma unroll
    for (int it = 0; it < 4; ++it) {
      const int d = d0 + 32 * it;
      u16 v[8];
#pragma unroll
      for (int e = 0; e < 8; ++e)
        v[e] = Ls[(k0 + (e & 3) + 8 * (e >> 2)) * 130 + d];
      u64 lo = (u64)v[0] | ((u64)v[1] << 16) | ((u64)v[2] << 32) | ((u64)v[3] << 48);
      u64 hi = (u64)v[4] | ((u64)v[5] << 16) | ((u64)v[6] << 32) | ((u64)v[7] << 48);
      u64* dst = (u64*)(vt + ((size_t)g * 128 + d) * 2048 + sb * 64 + c * 8);
      dst[0] = lo; dst[1] = hi;
    }
  }
}

// ---------------------------------------------------------------- flash attention
// r19 version (best): deferred cross-half max; 512 blocks x 256 thr = 4
// waves (2 qg x 2 k-halves); q64-tile pair (j, 31-j) sequential (33 iters);
// counted vmcnt(8) pipeline, 2 barriers/iter; zero-shuffle PV via
// sigma-ordered vt; XOR bank swizzles; defer-max; exp2-domain Q prescale.
__global__ __launch_bounds__(256, 2) void attn_kernel(const u16* __restrict__ qkv,
                                                      const u16* __restrict__ vt,
                                                      u16* __restrict__ ao) {
  __shared__ u16 Ks[2][64 * 128];   // [k][d], 16B chunks XORed by k&7 (32K)
  __shared__ u16 Vt[2][128 * 64];   // [d][sigma(k)], chunks XORed by d&7 (32K)

  const int t = threadIdx.x;
  const int lane = t & 63, w = t >> 6;
  const int l31 = lane & 31, hi = lane >> 5;
  const int qg = w >> 1, hi2 = w & 1;

  const int bid = blockIdx.x;
  const int g = bid & 7;                  // XCD group = (b, kvh)
  const int b = g >> 2, kvh = g & 3;
  const int idx = bid >> 3;
  const int h = kvh * 4 + (idx & 3);
  const int j = idx >> 2;                 // 0..15 -> pair (j, 31-j)

  const int kcol = 2048 + kvh * 128;
  const u16* vtg = vt + (size_t)g * 128 * 2048;

  const int krow_s = t >> 4, kchk = t & 15;   // K staging (4 GLD/thread)
  const int vd = t >> 3, vc = t & 7;          // V staging (4 GLD/thread)

#define STAGE_K(kb_, buf_) do {                                               \
    const size_t rb_ = (size_t)(b * 2048 + (kb_) * 64);                       \
    _Pragma("unroll")                                                         \
    for (int j_ = 0; j_ < 4; ++j_) {                                          \
      const int row_ = j_ * 16 + krow_s;                                      \
      GLD16(qkv + (rb_ + row_) * 3072 + kcol + ((kchk ^ (row_ & 7)) << 3),    \
            &Ks[buf_][(j_ * 256 + t) << 3]);                                  \
    } } while (0)

#define STAGE_V(kb_, buf_) do {                                               \
    _Pragma("unroll")                                                         \
    for (int j_ = 0; j_ < 4; ++j_) {                                          \
      const int d_ = j_ * 32 + vd;                                            \
      GLD16(vtg + (size_t)d_ * 2048 + (kb_) * 64 + ((vc ^ (d_ & 7)) << 3),    \
            &Vt[buf_][(j_ * 256 + t) << 3]);                                  \
    } } while (0)

  for (int ph = 0; ph < 2; ++ph) {
    const int qt64 = ph ? (31 - j) : j;
    const int q0 = qt64 * 64;
    const int nt = qt64 + 1;
    const int qrow = q0 + 32 * qg + l31;

    // Q fragments (B operand): col=q, k = st*16 + hi*8 + e (pre-scaled)
    bf16x8 qf[8];
    {
      const u16* qp = qkv + (size_t)(b * 2048 + qrow) * 3072 + h * 128 + hi * 8;
#pragma unroll
      for (int st = 0; st < 8; ++st) qf[st] = *(const bf16x8*)(qp + st * 16);
    }

    f32x16 o[4];
#pragma unroll
    for (int dt = 0; dt < 4; ++dt)
#pragma unroll
      for (int i = 0; i < 16; ++i) o[dt][i] = 0.f;
    float m2 = -1e30f, l = 0.f;

    // prologue: stage batches 0 and 1
    STAGE_K(0, 0);
    STAGE_V(0, 0);
    if (nt > 1) { STAGE_K(1, 1); STAGE_V(1, 1); }

    for (int kb = 0; kb < nt; ++kb) {
      const int cur = kb & 1;
      if (kb + 1 < nt) asm volatile("s_waitcnt vmcnt(8)" ::: "memory");
      else             asm volatile("s_waitcnt vmcnt(0)" ::: "memory");
      __builtin_amdgcn_s_barrier();
      __builtin_amdgcn_sched_barrier(0);

      // ---- S^T = K_half Q^T  (rows k of this wave's 32-half, cols q)
      f32x16 s;
#pragma unroll
      for (int i = 0; i < 16; ++i) s[i] = 0.f;
      const int kbase = (32 * hi2 + l31) * 128;
      const int ksw = l31 & 7;
      __builtin_amdgcn_s_setprio(1);
#pragma unroll
      for (int st = 0; st < 8; ++st) {
        bf16x8 ka = *(const bf16x8*)&Ks[cur][kbase + (((2 * st + hi) ^ ksw) << 3)];
        s = MFMA32(ka, qf[st], s);
      }
      __builtin_amdgcn_s_setprio(0);

      // ---- mask (diag only), max3-tree LOCAL row max (no cross-half shfl)
      const bool nomask = (kb < qt64) || (hi2 == 0 && qg == 1);
      if (!nomask) {
#pragma unroll
        for (int i = 0; i < 16; ++i) {
          const int kr = kb * 64 + 32 * hi2 + (i & 3) + 8 * (i >> 2) + 4 * hi;
          s[i] = (kr <= qrow) ? s[i] : -INFINITY;
        }
      }
      float a0 = fmax3(s[0], s[1], s[2]);
      float a1 = fmax3(s[3], s[4], s[5]);
      float a2 = fmax3(s[6], s[7], s[8]);
      float a3 = fmax3(s[9], s[10], s[11]);
      float a4 = fmax3(s[12], s[13], s[14]);
      float b0 = fmax3(a0, a1, s[15]);
      float b1 = fmax3(a2, a3, a4);
      float pm = fmaxf(b0, b1);
      // ---- defer-max rescale; __all spans all 64 lanes -> local test is
      // equivalent to full-row max test; shuffle only inside the rare branch.
      if (!__all(pm <= m2 + 8.f)) {
        const float pmf = fmaxf(pm, __shfl_xor(pm, 32));
        const float m2n = fmaxf(m2, pmf);
        const float fc = exp2f(m2 - m2n);
        m2 = m2n; l *= fc;
#pragma unroll
        for (int dt = 0; dt < 4; ++dt)
#pragma unroll
          for (int i = 0; i < 16; ++i) o[dt][i] *= fc;
      }
      // ---- P = exp2(z - m2), tree local sum (cross-hi deferred)
#pragma unroll
      for (int i = 0; i < 16; ++i) s[i] = exp2f(s[i] - m2);
      float t8[8];
#pragma unroll
      for (int i = 0; i < 8; ++i) t8[i] = s[i] + s[i + 8];
#pragma unroll
      for (int i = 0; i < 4; ++i) t8[i] = t8[i] + t8[i + 4];
      l += (t8[0] + t8[1]) + (t8[2] + t8[3]);
      // ---- P C-regs -> B-operand directly (sigma order, perm pack)
      union PB { u32 wd[4]; bf16x8 v; } p0u, p1u;
#pragma unroll
      for (int q_ = 0; q_ < 4; ++q_) {
        p0u.wd[q_] = pk2(s[2 * q_],     s[2 * q_ + 1]);
        p1u.wd[q_] = pk2(s[8 + 2 * q_], s[8 + 2 * q_ + 1]);
      }
      // ---- O^T += V^T_half P_half  (rows d, cols q)
      __builtin_amdgcn_s_setprio(1);
#pragma unroll
      for (int dt = 0; dt < 4; ++dt) {
        const int vrow = (dt * 32 + l31) * 64;
        const int dsw = l31 & 7;
        bf16x8 va0 = *(const bf16x8*)&Vt[cur][vrow + (((4 * hi2 + hi) ^ dsw) << 3)];
        o[dt] = MFMA32(va0, p0u.v, o[dt]);
        bf16x8 va1 = *(const bf16x8*)&Vt[cur][vrow + (((4 * hi2 + 2 + hi) ^ dsw) << 3)];
        o[dt] = MFMA32(va1, p1u.v, o[dt]);
      }
      __builtin_amdgcn_s_setprio(0);

      __builtin_amdgcn_s_barrier();          // all waves done reading buf[cur]
      if (kb + 2 < nt) { STAGE_K(kb + 2, cur); STAGE_V(kb + 2, cur); }
    }

    // ---- in-block merge of the two k-halves (per q-group)
    __syncthreads();                 // all compute done; Ks/Vt reusable
    const float l_tot = l + __shfl_xor(l, 32);
    float* Mrg = (float*)&Ks[0][0];
    float* Mlb = (float*)&Vt[0][0];
    const int sw8 = l31 & 7;
    if (hi2) {
#pragma unroll
      for (int dt = 0; dt < 4; ++dt) {
        const int rbase = ((qg * 4 + dt) * 32 + l31) * 32;
#pragma unroll
        for (int m_ = 0; m_ < 4; ++m_) {
          f32x4 cv;
          cv[0] = o[dt][4 * m_ + 0]; cv[1] = o[dt][4 * m_ + 1];
          cv[2] = o[dt][4 * m_ + 2]; cv[3] = o[dt][4 * m_ + 3];
          *(f32x4*)&Mrg[rbase + (((hi * 4 + m_) ^ sw8) << 2)] = cv;
        }
      }
      if (hi == 0) {
        Mlb[qg * 64 + l31] = m2;
        Mlb[qg * 64 + 32 + l31] = l_tot;
      }
    }
    __syncthreads();
    if (!hi2) {
      const float m1 = Mlb[qg * 64 + l31];
      const float l1 = Mlb[qg * 64 + 32 + l31];
      const float ms = fmaxf(m2, m1);
      const float w0 = exp2f(m2 - ms), w1 = exp2f(m1 - ms);
      const float inv = 1.f / (w0 * l_tot + w1 * l1);
      const float aw0 = w0 * inv, aw1 = w1 * inv;
      const size_t orow = (size_t)(b * 2048 + qrow) * 2048 + h * 128;
#pragma unroll
      for (int dt = 0; dt < 4; ++dt) {
        const int rbase = ((qg * 4 + dt) * 32 + l31) * 32;
#pragma unroll
        for (int m_ = 0; m_ < 4; ++m_) {
          f32x4 o1v = *(const f32x4*)&Mrg[rbase + (((hi * 4 + m_) ^ sw8) << 2)];
          u64 val = 0;
#pragma unroll
          for (int r = 0; r < 4; ++r) {
            __hip_bfloat16 hb =
                __float2bfloat16(aw0 * o[dt][4 * m_ + r] + aw1 * o1v[r]);
            val |= (u64)(*(u16*)&hb) << (16 * r);
          }
          *(u64*)&ao[orow + dt * 32 + 8 * m_ + 4 * hi] = val;
        }
      }
    }
    __syncthreads();                 // protect Mrg/Mlb before next-phase staging
  }
#undef STAGE_K
#undef STAGE_V
}

// ---------------------------------------------------------------- launch
extern "C" void kernel_launch(void* const* d_in, const int* in_sizes, int n_in,
                              void* d_out, int out_size, void* d_ws, size_t ws_size,
                              hipStream_t stream) {
  const float* x  = (const float*)d_in[0];
  const float* wq = (const float*)d_in[2];
  const float* wk = (const float*)d_in[3];
  const float* wv = (const float*)d_in[4];
  const float* wo = (const float*)d_in[5];
  float* out = (float*)d_out;

  u16* xb   = (u16*)d_ws;                       // x bf16   [4096][2048]
  u16* wqkv = xb + (size_t)8388608;             // W bf16   [3072][2048]
  u16* qkv  = wqkv + (size_t)6291456;           // qkv      [4096][3072]
  u16* vtg  = qkv + (size_t)12582912;           // V^T      [8][128][2048]
  u16* wob  = vtg + (size_t)2097152;            // wo bf16  [2048][2048]
  u16* ao   = xb;                               // attn out [4096][2048] (reuse xb)

  cast_all<<<18432, 256, 0, stream>>>(x, wq, wk, wv, wo, xb, wqkv, wob);

  gemm_k64<u16><<<dim3(12, 16), 512, 0, stream>>>(xb, wqkv, qkv, 4096, 3072, 2048);

  rope_vtrans<<<20736, 256, 0, stream>>>(qkv, vtg);

  attn_kernel<<<512, 256, 0, stream>>>(qkv, vtg, ao);

  gemm_sm<float><<<dim3(16, 32), 256, 0, stream>>>(ao, wob, out, 4096, 2048, 2048);
}

// Round 24
// 192.852 us; speedup vs baseline: 1.0193x; 1.0025x over previous
//
#include <hip/hip_runtime.h>
#include <hip/hip_bf16.h>

typedef unsigned short u16;
typedef unsigned int   u32;
typedef unsigned long long u64;
typedef __attribute__((ext_vector_type(8))) short bf16x8;
typedef __attribute__((ext_vector_type(4))) float f32x4;
typedef __attribute__((ext_vector_type(16))) float f32x16;

#define MFMA16(a,b,c) __builtin_amdgcn_mfma_f32_16x16x32_bf16((a),(b),(c),0,0,0)
#define MFMA32(a,b,c) __builtin_amdgcn_mfma_f32_32x32x16_bf16((a),(b),(c),0,0,0)

#define GLD16(gp, lp) __builtin_amdgcn_global_load_lds( \
    (const __attribute__((address_space(1))) void*)(gp), \
    (__attribute__((address_space(3))) void*)(lp), 16, 0, 0)

__device__ inline u32 pkbf(float a, float b) {
  __hip_bfloat16 ha = __float2bfloat16(a), hb = __float2bfloat16(b);
  return (u32)(*(u16*)&ha) | ((u32)(*(u16*)&hb) << 16);
}
__device__ inline float b2f(u16 x) {
  __hip_bfloat16 h; *(u16*)&h = x; return __bfloat162float(h);
}
// fast bf16 pair pack: round (+0x8000) then byte-perm the two high halves
__device__ inline u32 pk2(float a, float b) {
  u32 ua = __builtin_bit_cast(u32, a) + 0x8000u;
  u32 ub = __builtin_bit_cast(u32, b) + 0x8000u;
  return __builtin_amdgcn_perm(ub, ua, 0x07060302u);
}
__device__ inline float fmax3(float a, float b, float c) {
  return fmaxf(fmaxf(a, b), c);
}

// ---------------------------------------------------------------- fused casts
// 32B-read / 16B-write per thread (two float4 loads -> one uint4 store).
// All segment boundaries are EVEN in float4 units, so a thread's pair never
// straddles segments. 9216 blocks.
__global__ __launch_bounds__(256) void cast_all(const float* __restrict__ x,
                                                const float* __restrict__ wq,
                                                const float* __restrict__ wk,
                                                const float* __restrict__ wv,
                                                const float* __restrict__ wo,
                                                u16* __restrict__ xb,
                                                u16* __restrict__ wqkv,
                                                u16* __restrict__ wob) {
  const int j = blockIdx.x * 256 + threadIdx.x;
  const int i = j * 2;                        // float4 index (even)
  const float* src; u16* dst; int off;
  if (i < 2097152)      { src = x;  dst = xb;                 off = 0; }
  else if (i < 3145728) { src = wq; dst = wqkv;               off = 2097152; }
  else if (i < 3407872) { src = wk; dst = wqkv + 4194304;     off = 3145728; }
  else if (i < 3670016) { src = wv; dst = wqkv + 5242880;     off = 3407872; }
  else                  { src = wo; dst = wob;                off = 3670016; }
  const int k = i - off;
  float4 v0 = reinterpret_cast<const float4*>(src)[k];
  float4 v1 = reinterpret_cast<const float4*>(src)[k + 1];
  uint4 pk;
  pk.x = pkbf(v0.x, v0.y); pk.y = pkbf(v0.z, v0.w);
  pk.z = pkbf(v1.x, v1.y); pk.w = pkbf(v1.z, v1.w);
  reinterpret_cast<uint4*>(dst)[k >> 1] = pk;
}

__device__ inline void cstore(u16* C, size_t i, float v) {
  __hip_bfloat16 h = __float2bfloat16(v); C[i] = *(u16*)&h;
}
__device__ inline void cstore(float* C, size_t i, float v) { C[i] = v; }

// ---------------------------------------------------------------- GEMM 256x256 BK=64
// C = A * B^T. 512 thr = 8 waves (2M x 4N), per-wave 128x64 (acc[8][4]).
// 128 KiB LDS dbuf; per buffer 4 regions (u16): A-ks0 [0,8K) | A-ks1 [8K,16K)
// | B-ks0 [16K,24K) | B-ks1 [24K,32K). Each region: 256 rows x 32 u16,
// slot-linear (slot=4*row+q -> slot*16B), source pre-swizzled with the
// PROVEN 2-way-free key q_log = q_phys ^ ((row>>1)&3) (row stride 64B).
// Schedule per K-tile x: 4 phases of 16 MFMA; stage one unit of tile x+1
// per phase in consumption order (A0,B0,A1,B1); TWO counted vmcnt(4)
// checkpoints (before P0 and P2) + 2 barriers per 64-MFMA tile; never a
// full drain mid-loop. (r21/r23 measured best: ~59us @ 192 blocks.)
template<typename OutT>
__global__ __launch_bounds__(512, 2) void gemm_k64(const u16* __restrict__ A,
                                                   const u16* __restrict__ B,
                                                   OutT* __restrict__ C,
                                                   int M, int N, int K) {
  __shared__ u16 SM[65536];   // 128 KiB

  const int t = threadIdx.x;
  const int lane = t & 63, wid = t >> 6;
  const int l15 = lane & 15, l4 = lane >> 4;
  const int wr = wid >> 2, wc = wid & 3;

  const int nwg = gridDim.x * gridDim.y;     // % 8 == 0
  int lid = blockIdx.y * gridDim.x + blockIdx.x;
  lid = (lid & 7) * (nwg >> 3) + (lid >> 3);
  const int m0 = (lid / gridDim.x) * 256, n0 = (lid % gridDim.x) * 256;

  // staging: slot s in {t, t+512}; row = s>>2, q_phys = s&3,
  // logical chunk = q_phys ^ ((row>>1)&3); global kcol = x*64 + ks*32 + lq*8
  const int r0 = t >> 2, q0p = t & 3;
  const int lq0 = q0p ^ ((r0 >> 1) & 3);
  const int r1 = r0 + 128;
  const int lq1 = q0p ^ ((r1 >> 1) & 3);
  const u16* Ap0 = A + (size_t)(m0 + r0) * K + lq0 * 8;
  const u16* Ap1 = A + (size_t)(m0 + r1) * K + lq1 * 8;
  const u16* Bp0 = B + (size_t)(n0 + r0) * K + lq0 * 8;
  const u16* Bp1 = B + (size_t)(n0 + r1) * K + lq1 * 8;

#define STG_A(x_, ks_) do {                                                   \
    const int bb_ = (((x_) & 1) << 15) + ((ks_) << 13);                       \
    GLD16(Ap0 + (x_) * 64 + (ks_) * 32, &SM[bb_ + t * 8]);                    \
    GLD16(Ap1 + (x_) * 64 + (ks_) * 32, &SM[bb_ + 4096 + t * 8]); } while (0)
#define STG_B(x_, ks_) do {                                                   \
    const int bb_ = (((x_) & 1) << 15) + 16384 + ((ks_) << 13);               \
    GLD16(Bp0 + (x_) * 64 + (ks_) * 32, &SM[bb_ + t * 8]);                    \
    GLD16(Bp1 + (x_) * 64 + (ks_) * 32, &SM[bb_ + 4096 + t * 8]); } while (0)

  // fragment reads: q = l4 ^ ((l15>>1)&3) (2-way free; row stride 64B)
  const int q = l4 ^ ((l15 >> 1) & 3);
  const int arow = wr * 128 + l15;     // + mi*16 (+64 for m-frags 4-7)
  const int brow = wc * 64 + l15;      // + ni*16

  f32x4 acc[8][4] = {};
  const int nk = K >> 6;

  // prologue: tile 0 units in consumption order
  STG_A(0, 0); STG_B(0, 0); STG_A(0, 1); STG_B(0, 1);

  for (int x = 0; x < nk; ++x) {
    const int bufb = (x & 1) << 15;
    const bool pre = (x + 1 < nk);

    // ---- checkpoint: A0x, B0x landed (A1x, B1x stay in flight)
    asm volatile("s_waitcnt vmcnt(4)" ::: "memory");
    __builtin_amdgcn_s_barrier();
    __builtin_amdgcn_sched_barrier(0);

    bf16x8 af[4], bfr[4];
    // ---- P0: ks0, m-frags 0-3 (8 ds_read)
#pragma unroll
    for (int i = 0; i < 4; ++i)
      af[i] = *(const bf16x8*)&SM[bufb + (arow + i * 16) * 32 + q * 8];
#pragma unroll
    for (int i = 0; i < 4; ++i)
      bfr[i] = *(const bf16x8*)&SM[bufb + 16384 + (brow + i * 16) * 32 + q * 8];
    if (pre) STG_A(x + 1, 0);
    asm volatile("s_waitcnt lgkmcnt(0)" ::: "memory");
    __builtin_amdgcn_sched_barrier(0);
    __builtin_amdgcn_s_setprio(1);
#pragma unroll
    for (int mi = 0; mi < 4; ++mi)
#pragma unroll
      for (int ni = 0; ni < 4; ++ni)
        acc[mi][ni] = MFMA16(af[mi], bfr[ni], acc[mi][ni]);
    __builtin_amdgcn_s_setprio(0);

    // ---- P1: ks0, m-frags 4-7 (4 ds_read; bfr reused)
#pragma unroll
    for (int i = 0; i < 4; ++i)
      af[i] = *(const bf16x8*)&SM[bufb + (arow + 64 + i * 16) * 32 + q * 8];
    if (pre) STG_B(x + 1, 0);
    asm volatile("s_waitcnt lgkmcnt(0)" ::: "memory");
    __builtin_amdgcn_sched_barrier(0);
    __builtin_amdgcn_s_setprio(1);
#pragma unroll
    for (int mi = 0; mi < 4; ++mi)
#pragma unroll
      for (int ni = 0; ni < 4; ++ni)
        acc[4 + mi][ni] = MFMA16(af[mi], bfr[ni], acc[4 + mi][ni]);
    __builtin_amdgcn_s_setprio(0);

    // ---- checkpoint: A1x, B1x landed (next tile's A0,B0 stay in flight)
    if (pre) asm volatile("s_waitcnt vmcnt(4)" ::: "memory");
    else     asm volatile("s_waitcnt vmcnt(0)" ::: "memory");
    __builtin_amdgcn_s_barrier();
    __builtin_amdgcn_sched_barrier(0);

    // ---- P2: ks1, m-frags 0-3 (8 ds_read)
#pragma unroll
    for (int i = 0; i < 4; ++i)
      af[i] = *(const bf16x8*)&SM[bufb + 8192 + (arow + i * 16) * 32 + q * 8];
#pragma unroll
    for (int i = 0; i < 4; ++i)
      bfr[i] = *(const bf16x8*)&SM[bufb + 24576 + (brow + i * 16) * 32 + q * 8];
    if (pre) STG_A(x + 1, 1);
    asm volatile("s_waitcnt lgkmcnt(0)" ::: "memory");
    __builtin_amdgcn_sched_barrier(0);
    __builtin_amdgcn_s_setprio(1);
#pragma unroll
    for (int mi = 0; mi < 4; ++mi)
#pragma unroll
      for (int ni = 0; ni < 4; ++ni)
        acc[mi][ni] = MFMA16(af[mi], bfr[ni], acc[mi][ni]);
    __builtin_amdgcn_s_setprio(0);

    // ---- P3: ks1, m-frags 4-7 (4 ds_read)
#pragma unroll
    for (int i = 0; i < 4; ++i)
      af[i] = *(const bf16x8*)&SM[bufb + 8192 + (arow + 64 + i * 16) * 32 + q * 8];
    if (pre) STG_B(x + 1, 1);
    asm volatile("s_waitcnt lgkmcnt(0)" ::: "memory");
    __builtin_amdgcn_sched_barrier(0);
    __builtin_amdgcn_s_setprio(1);
#pragma unroll
    for (int mi = 0; mi < 4; ++mi)
#pragma unroll
      for (int ni = 0; ni < 4; ++ni)
        acc[4 + mi][ni] = MFMA16(af[mi], bfr[ni], acc[4 + mi][ni]);
    __builtin_amdgcn_s_setprio(0);
  }

  const int crow = m0 + wr * 128 + (l4 << 2);
  const int ccol = n0 + wc * 64 + l15;
#pragma unroll
  for (int mi = 0; mi < 8; ++mi)
#pragma unroll
    for (int ni = 0; ni < 4; ++ni)
#pragma unroll
      for (int r = 0; r < 4; ++r)
        cstore(C, (size_t)(crow + mi * 16 + r) * N + (ccol + ni * 16), acc[mi][ni][r]);
#undef STG_A
#undef STG_B
}

// ---------------------------------------------------------------- GEMM 128x128
// Output projection. 256 thr = 4 waves (2M x 2N), triple-buffered LDS,
// counted vmcnt; 0-conflict chunk swizzle (r16-r20 proven).
template<typename OutT>
__global__ __launch_bounds__(256, 4) void gemm_sm(const u16* __restrict__ A,
                                                  const u16* __restrict__ B,
                                                  OutT* __restrict__ C,
                                                  int M, int N, int K) {
  __shared__ u16 As[3][128 * 32];   // 24K
  __shared__ u16 Bs[3][128 * 32];   // 24K

  const int t = threadIdx.x;
  const int lane = t & 63, wid = t >> 6;
  const int l15 = lane & 15, l4 = lane >> 4;
  const int wr = wid >> 1, wc = wid & 1;

  const int nwg = gridDim.x * gridDim.y;
  int lid = blockIdx.y * gridDim.x + blockIdx.x;
  lid = (lid & 7) * (nwg >> 3) + (lid >> 3);
  const int m0 = (lid / gridDim.x) * 128, n0 = (lid % gridDim.x) * 128;

  const int ra0 = t >> 2,         ca0 = (t & 3) ^ ((ra0 >> 1) & 3);
  const int ra1 = (t + 256) >> 2, ca1 = (t & 3) ^ ((ra1 >> 1) & 3);
  const u16* Ag0 = A + (size_t)(m0 + ra0) * K + ca0 * 8;
  const u16* Ag1 = A + (size_t)(m0 + ra1) * K + ca1 * 8;
  const u16* Bg0 = B + (size_t)(n0 + ra0) * K + ca0 * 8;
  const u16* Bg1 = B + (size_t)(n0 + ra1) * K + ca1 * 8;

#define STAGE(k0_, buf_) do {                                                 \
    GLD16(Ag0 + (k0_), &As[buf_][t * 8]);                                     \
    GLD16(Ag1 + (k0_), &As[buf_][2048 + t * 8]);                              \
    GLD16(Bg0 + (k0_), &Bs[buf_][t * 8]);                                     \
    GLD16(Bg1 + (k0_), &Bs[buf_][2048 + t * 8]);                              \
  } while (0)

  const int nk = K >> 5;
  const int ks = (l15 >> 1) & 3;
  const int coff = ((l4 ^ ks) << 3);

  f32x4 acc[4][4] = {};

  STAGE(0, 0);
  if (nk > 1) STAGE(32, 1);
  if (nk > 2) STAGE(64, 2);

  int cur = 0;
  for (int j = 0; j < nk; ++j) {
    if (j + 2 < nk)      asm volatile("s_waitcnt vmcnt(8)" ::: "memory");
    else if (j + 1 < nk) asm volatile("s_waitcnt vmcnt(4)" ::: "memory");
    else                 asm volatile("s_waitcnt vmcnt(0)" ::: "memory");
    __builtin_amdgcn_s_barrier();
    __builtin_amdgcn_sched_barrier(0);

    bf16x8 af[4], bfr[4];
#pragma unroll
    for (int mi = 0; mi < 4; ++mi)
      af[mi] = *(const bf16x8*)&As[cur][(wr * 64 + mi * 16 + l15) * 32 + coff];
#pragma unroll
    for (int ni = 0; ni < 4; ++ni)
      bfr[ni] = *(const bf16x8*)&Bs[cur][(wc * 64 + ni * 16 + l15) * 32 + coff];
    __builtin_amdgcn_s_setprio(1);
#pragma unroll
    for (int mi = 0; mi < 4; ++mi)
#pragma unroll
      for (int ni = 0; ni < 4; ++ni)
        acc[mi][ni] = MFMA16(af[mi], bfr[ni], acc[mi][ni]);
    __builtin_amdgcn_s_setprio(0);

    __builtin_amdgcn_s_barrier();
    if (j + 3 < nk) STAGE((j + 3) << 5, cur);
    cur = (cur == 2) ? 0 : cur + 1;
  }

  const int crow = m0 + wr * 64 + (l4 << 2);
  const int ccol = n0 + wc * 64 + l15;
#pragma unroll
  for (int mi = 0; mi < 4; ++mi)
#pragma unroll
    for (int ni = 0; ni < 4; ++ni)
#pragma unroll
      for (int r = 0; r < 4; ++r)
        cstore(C, (size_t)(crow + mi * 16 + r) * N + (ccol + ni * 16), acc[mi][ni][r]);
#undef STAGE
}

// ---------------------------------------------------------------- RMSNorm+RoPE | Vtrans
// Merged launch: blocks [0,20480) do rmsrope (qkv cols < 2560); blocks
// [20480, 20736) do the V transpose (reads cols >= 2560) -> independent.
__global__ __launch_bounds__(256) void rope_vtrans(u16* __restrict__ qkv,
                                                   u16* __restrict__ vt) {
  __shared__ u16 Ls[64 * 130];
  const int bid = blockIdx.x;
  const int t = threadIdx.x;
  if (bid < 20480) {
    const int lane = t & 63;
    const int gw = bid * 4 + (t >> 6);
    const int row = gw / 20;
    const int hd = gw - row * 20;
    const int col = (hd < 16) ? hd * 128 : 2048 + (hd - 16) * 128;
    const size_t base = (size_t)row * 3072 + col;
    float x1 = b2f(qkv[base + lane]);
    float x2 = b2f(qkv[base + 64 + lane]);
    float ss = x1 * x1 + x2 * x2;
#pragma unroll
    for (int off = 32; off >= 1; off >>= 1) ss += __shfl_xor(ss, off, 64);
    const float qsc = (hd < 16) ? (0.08838834764831845f * 1.44269504088896340f)
                                : 1.0f;
    const float sc = rsqrtf(ss * (1.0f / 128.0f) + 1e-6f) * qsc;
    const int pos = row & 2047;
    const float inv_freq = exp2f(-(float)lane * (13.287712379549449f / 64.0f));
    float sn, cs;
    sincosf((float)pos * inv_freq, &sn, &cs);
    const float a = x1 * sc, b2 = x2 * sc;
    __hip_bfloat16 o1 = __float2bfloat16(a * cs - b2 * sn);
    __hip_bfloat16 o2 = __float2bfloat16(a * sn + b2 * cs);
    qkv[base + lane] = *(u16*)&o1;
    qkv[base + 64 + lane] = *(u16*)&o2;
  } else {
    const int vb = bid - 20480;
    const int g = vb & 7, sb = vb >> 3;
    const int b = g >> 2, kvh = g & 3;
    const int vcol = 2560 + kvh * 128;
    {
      const int row = t >> 4, dch = t & 15;
      const u16* src = qkv + (size_t)(b * 2048 + sb * 64 + row) * 3072 + vcol + dch * 8;
#pragma unroll
      for (int it = 0; it < 4; ++it) {
        bf16x8 v = *(const bf16x8*)(src + (size_t)it * 16 * 3072);
        *(bf16x8*)&Ls[(row + it * 16) * 130 + dch * 8] = v;
      }
    }
    __syncthreads();
    const int c = t & 7, d0 = t >> 3;
    const int k0 = 4 * (8 * (c >> 2) + 4 * ((c >> 1) & 1) + (c & 1));
#pragma unroll
    for (int it = 0; it < 4; ++it) {
      const int d = d0 + 32 * it;
      u16 v[8];
#pragma unroll
      for (int e = 0; e < 8; ++e)
        v[e] = Ls[(k0 + (e & 3) + 8 * (e >> 2)) * 130 + d];
      u64 lo = (u64)v[0] | ((u64)v[1] << 16) | ((u64)v[2] << 32) | ((u64)v[3] << 48);
      u64 hi = (u64)v[4] | ((u64)v[5] << 16) | ((u64)v[6] << 32) | ((u64)v[7] << 48);
      u64* dst = (u64*)(vt + ((size_t)g * 128 + d) * 2048 + sb * 64 + c * 8);
      dst[0] = lo; dst[1] = hi;
    }
  }
}

// ---------------------------------------------------------------- flash attention
// r19 version (best): deferred cross-half max; 512 blocks x 256 thr = 4
// waves (2 qg x 2 k-halves); q64-tile pair (j, 31-j) sequential (33 iters);
// counted vmcnt(8) pipeline, 2 barriers/iter; zero-shuffle PV via
// sigma-ordered vt; XOR bank swizzles; defer-max; exp2-domain Q prescale.
__global__ __launch_bounds__(256, 2) void attn_kernel(const u16* __restrict__ qkv,
                                                      const u16* __restrict__ vt,
                                                      u16* __restrict__ ao) {
  __shared__ u16 Ks[2][64 * 128];   // [k][d], 16B chunks XORed by k&7 (32K)
  __shared__ u16 Vt[2][128 * 64];   // [d][sigma(k)], chunks XORed by d&7 (32K)

  const int t = threadIdx.x;
  const int lane = t & 63, w = t >> 6;
  const int l31 = lane & 31, hi = lane >> 5;
  const int qg = w >> 1, hi2 = w & 1;

  const int bid = blockIdx.x;
  const int g = bid & 7;                  // XCD group = (b, kvh)
  const int b = g >> 2, kvh = g & 3;
  const int idx = bid >> 3;
  const int h = kvh * 4 + (idx & 3);
  const int j = idx >> 2;                 // 0..15 -> pair (j, 31-j)

  const int kcol = 2048 + kvh * 128;
  const u16* vtg = vt + (size_t)g * 128 * 2048;

  const int krow_s = t >> 4, kchk = t & 15;   // K staging (4 GLD/thread)
  const int vd = t >> 3, vc = t & 7;          // V staging (4 GLD/thread)

#define STAGE_K(kb_, buf_) do {                                               \
    const size_t rb_ = (size_t)(b * 2048 + (kb_) * 64);                       \
    _Pragma("unroll")                                                         \
    for (int j_ = 0; j_ < 4; ++j_) {                                          \
      const int row_ = j_ * 16 + krow_s;                                      \
      GLD16(qkv + (rb_ + row_) * 3072 + kcol + ((kchk ^ (row_ & 7)) << 3),    \
            &Ks[buf_][(j_ * 256 + t) << 3]);                                  \
    } } while (0)

#define STAGE_V(kb_, buf_) do {                                               \
    _Pragma("unroll")                                                         \
    for (int j_ = 0; j_ < 4; ++j_) {                                          \
      const int d_ = j_ * 32 + vd;                                            \
      GLD16(vtg + (size_t)d_ * 2048 + (kb_) * 64 + ((vc ^ (d_ & 7)) << 3),    \
            &Vt[buf_][(j_ * 256 + t) << 3]);                                  \
    } } while (0)

  for (int ph = 0; ph < 2; ++ph) {
    const int qt64 = ph ? (31 - j) : j;
    const int q0 = qt64 * 64;
    const int nt = qt64 + 1;
    const int qrow = q0 + 32 * qg + l31;

    // Q fragments (B operand): col=q, k = st*16 + hi*8 + e (pre-scaled)
    bf16x8 qf[8];
    {
      const u16* qp = qkv + (size_t)(b * 2048 + qrow) * 3072 + h * 128 + hi * 8;
#pragma unroll
      for (int st = 0; st < 8; ++st) qf[st] = *(const bf16x8*)(qp + st * 16);
    }

    f32x16 o[4];
#pragma unroll
    for (int dt = 0; dt < 4; ++dt)
#pragma unroll
      for (int i = 0; i < 16; ++i) o[dt][i] = 0.f;
    float m2 = -1e30f, l = 0.f;

    // prologue: stage batches 0 and 1
    STAGE_K(0, 0);
    STAGE_V(0, 0);
    if (nt > 1) { STAGE_K(1, 1); STAGE_V(1, 1); }

    for (int kb = 0; kb < nt; ++kb) {
      const int cur = kb & 1;
      if (kb + 1 < nt) asm volatile("s_waitcnt vmcnt(8)" ::: "memory");
      else             asm volatile("s_waitcnt vmcnt(0)" ::: "memory");
      __builtin_amdgcn_s_barrier();
      __builtin_amdgcn_sched_barrier(0);

      // ---- S^T = K_half Q^T  (rows k of this wave's 32-half, cols q)
      f32x16 s;
#pragma unroll
      for (int i = 0; i < 16; ++i) s[i] = 0.f;
      const int kbase = (32 * hi2 + l31) * 128;
      const int ksw = l31 & 7;
      __builtin_amdgcn_s_setprio(1);
#pragma unroll
      for (int st = 0; st < 8; ++st) {
        bf16x8 ka = *(const bf16x8*)&Ks[cur][kbase + (((2 * st + hi) ^ ksw) << 3)];
        s = MFMA32(ka, qf[st], s);
      }
      __builtin_amdgcn_s_setprio(0);

      // ---- mask (diag only), max3-tree LOCAL row max (no cross-half shfl)
      const bool nomask = (kb < qt64) || (hi2 == 0 && qg == 1);
      if (!nomask) {
#pragma unroll
        for (int i = 0; i < 16; ++i) {
          const int kr = kb * 64 + 32 * hi2 + (i & 3) + 8 * (i >> 2) + 4 * hi;
          s[i] = (kr <= qrow) ? s[i] : -INFINITY;
        }
      }
      float a0 = fmax3(s[0], s[1], s[2]);
      float a1 = fmax3(s[3], s[4], s[5]);
      float a2 = fmax3(s[6], s[7], s[8]);
      float a3 = fmax3(s[9], s[10], s[11]);
      float a4 = fmax3(s[12], s[13], s[14]);
      float b0 = fmax3(a0, a1, s[15]);
      float b1 = fmax3(a2, a3, a4);
      float pm = fmaxf(b0, b1);
      // ---- defer-max rescale; __all spans all 64 lanes -> local test is
      // equivalent to full-row max test; shuffle only inside the rare branch.
      if (!__all(pm <= m2 + 8.f)) {
        const float pmf = fmaxf(pm, __shfl_xor(pm, 32));
        const float m2n = fmaxf(m2, pmf);
        const float fc = exp2f(m2 - m2n);
        m2 = m2n; l *= fc;
#pragma unroll
        for (int dt = 0; dt < 4; ++dt)
#pragma unroll
          for (int i = 0; i < 16; ++i) o[dt][i] *= fc;
      }
      // ---- P = exp2(z - m2), tree local sum (cross-hi deferred)
#pragma unroll
      for (int i = 0; i < 16; ++i) s[i] = exp2f(s[i] - m2);
      float t8[8];
#pragma unroll
      for (int i = 0; i < 8; ++i) t8[i] = s[i] + s[i + 8];
#pragma unroll
      for (int i = 0; i < 4; ++i) t8[i] = t8[i] + t8[i + 4];
      l += (t8[0] + t8[1]) + (t8[2] + t8[3]);
      // ---- P C-regs -> B-operand directly (sigma order, perm pack)
      union PB { u32 wd[4]; bf16x8 v; } p0u, p1u;
#pragma unroll
      for (int q_ = 0; q_ < 4; ++q_) {
        p0u.wd[q_] = pk2(s[2 * q_],     s[2 * q_ + 1]);
        p1u.wd[q_] = pk2(s[8 + 2 * q_], s[8 + 2 * q_ + 1]);
      }
      // ---- O^T += V^T_half P_half  (rows d, cols q)
      __builtin_amdgcn_s_setprio(1);
#pragma unroll
      for (int dt = 0; dt < 4; ++dt) {
        const int vrow = (dt * 32 + l31) * 64;
        const int dsw = l31 & 7;
        bf16x8 va0 = *(const bf16x8*)&Vt[cur][vrow + (((4 * hi2 + hi) ^ dsw) << 3)];
        o[dt] = MFMA32(va0, p0u.v, o[dt]);
        bf16x8 va1 = *(const bf16x8*)&Vt[cur][vrow + (((4 * hi2 + 2 + hi) ^ dsw) << 3)];
        o[dt] = MFMA32(va1, p1u.v, o[dt]);
      }
      __builtin_amdgcn_s_setprio(0);

      __builtin_amdgcn_s_barrier();          // all waves done reading buf[cur]
      if (kb + 2 < nt) { STAGE_K(kb + 2, cur); STAGE_V(kb + 2, cur); }
    }

    // ---- in-block merge of the two k-halves (per q-group)
    __syncthreads();                 // all compute done; Ks/Vt reusable
    const float l_tot = l + __shfl_xor(l, 32);
    float* Mrg = (float*)&Ks[0][0];
    float* Mlb = (float*)&Vt[0][0];
    const int sw8 = l31 & 7;
    if (hi2) {
#pragma unroll
      for (int dt = 0; dt < 4; ++dt) {
        const int rbase = ((qg * 4 + dt) * 32 + l31) * 32;
#pragma unroll
        for (int m_ = 0; m_ < 4; ++m_) {
          f32x4 cv;
          cv[0] = o[dt][4 * m_ + 0]; cv[1] = o[dt][4 * m_ + 1];
          cv[2] = o[dt][4 * m_ + 2]; cv[3] = o[dt][4 * m_ + 3];
          *(f32x4*)&Mrg[rbase + (((hi * 4 + m_) ^ sw8) << 2)] = cv;
        }
      }
      if (hi == 0) {
        Mlb[qg * 64 + l31] = m2;
        Mlb[qg * 64 + 32 + l31] = l_tot;
      }
    }
    __syncthreads();
    if (!hi2) {
      const float m1 = Mlb[qg * 64 + l31];
      const float l1 = Mlb[qg * 64 + 32 + l31];
      const float ms = fmaxf(m2, m1);
      const float w0 = exp2f(m2 - ms), w1 = exp2f(m1 - ms);
      const float inv = 1.f / (w0 * l_tot + w1 * l1);
      const float aw0 = w0 * inv, aw1 = w1 * inv;
      const size_t orow = (size_t)(b * 2048 + qrow) * 2048 + h * 128;
#pragma unroll
      for (int dt = 0; dt < 4; ++dt) {
        const int rbase = ((qg * 4 + dt) * 32 + l31) * 32;
#pragma unroll
        for (int m_ = 0; m_ < 4; ++m_) {
          f32x4 o1v = *(const f32x4*)&Mrg[rbase + (((hi * 4 + m_) ^ sw8) << 2)];
          u64 val = 0;
#pragma unroll
          for (int r = 0; r < 4; ++r) {
            __hip_bfloat16 hb =
                __float2bfloat16(aw0 * o[dt][4 * m_ + r] + aw1 * o1v[r]);
            val |= (u64)(*(u16*)&hb) << (16 * r);
          }
          *(u64*)&ao[orow + dt * 32 + 8 * m_ + 4 * hi] = val;
        }
      }
    }
    __syncthreads();                 // protect Mrg/Mlb before next-phase staging
  }
#undef STAGE_K
#undef STAGE_V
}

// ---------------------------------------------------------------- launch
extern "C" void kernel_launch(void* const* d_in, const int* in_sizes, int n_in,
                              void* d_out, int out_size, void* d_ws, size_t ws_size,
                              hipStream_t stream) {
  const float* x  = (const float*)d_in[0];
  const float* wq = (const float*)d_in[2];
  const float* wk = (const float*)d_in[3];
  const float* wv = (const float*)d_in[4];
  const float* wo = (const float*)d_in[5];
  float* out = (float*)d_out;

  u16* xb   = (u16*)d_ws;                       // x bf16   [4096][2048]
  u16* wqkv = xb + (size_t)8388608;             // W bf16   [3072][2048]
  u16* qkv  = wqkv + (size_t)6291456;           // qkv      [4096][3072]
  u16* vtg  = qkv + (size_t)12582912;           // V^T      [8][128][2048]
  u16* wob  = vtg + (size_t)2097152;            // wo bf16  [2048][2048]
  u16* ao   = xb;                               // attn out [4096][2048] (reuse xb)

  cast_all<<<9216, 256, 0, stream>>>(x, wq, wk, wv, wo, xb, wqkv, wob);

  gemm_k64<u16><<<dim3(12, 16), 512, 0, stream>>>(xb, wqkv, qkv, 4096, 3072, 2048);

  rope_vtrans<<<20736, 256, 0, stream>>>(qkv, vtg);

  attn_kernel<<<512, 256, 0, stream>>>(qkv, vtg, ao);

  gemm_sm<float><<<dim3(16, 32), 256, 0, stream>>>(ao, wob, out, 4096, 2048, 2048);
}